// Round 3
// baseline (2647.228 us; speedup 1.0000x reference)
//
#include <hip/hip_runtime.h>
#include <hip/hip_cooperative_groups.h>

namespace cgx = cooperative_groups;

static constexpr int NN  = 6144;
static constexpr int NE  = 98304;
static constexpr int NF  = 128;
static constexpr int NT  = 16;
static constexpr int MN  = 10;
static constexpr int NCG = 5;
static constexpr int NSK = 50;
static constexpr int WPR = NN / 32;      // 192 words per bitmap row
static constexpr int TPB = 768;
static constexpr int NBLK = 256;
static constexpr int RPT = NN / TPB;     // 8 rows/thread -> E[8][10] = 80 VGPRs
static constexpr int STR = 16;           // padded row stride for gathered dT (64B-aligned rows)
static constexpr int NW  = TPB / 64;     // 12 waves

static_assert(TPB * RPT == NN, "row mapping");

// workspace layout (float elements). BM (bitmap) aliases the D+dT region: BM is
// setup-only, D/dT are CG-loop-only.
static constexpr size_t SZ_CMP = (size_t)NT * NN * MN;   // 983040
static constexpr size_t SZ_PAD = (size_t)NT * NN * STR;  // 1572864
static constexpr size_t OFF_M   = 0;
static constexpr size_t OFF_T   = OFF_M + SZ_CMP;
static constexpr size_t OFF_C   = OFF_T + SZ_CMP;
static constexpr size_t OFF_D   = OFF_C + SZ_CMP;        // compact (never gathered)
static constexpr size_t OFF_DT  = OFF_D + SZ_CMP;        // padded stride 16 (gathered)
static constexpr size_t OFF_RS  = OFF_DT + SZ_PAD;
static constexpr size_t OFF_DEG = OFF_RS + NN;
static constexpr size_t OFF_CI  = OFF_DEG + NN;
static constexpr size_t OFF_NNZ = OFF_CI + 2 * NE;
// total ~5.71M floats ~= 22.9 MB

__global__ __launch_bounds__(TPB, 3) void tfgw_kernel(
    const float* __restrict__ x, const void* __restrict__ eiv,
    const float* __restrict__ tpl, const float* __restrict__ tf,
    const float* __restrict__ q0, const float* __restrict__ a0,
    float* __restrict__ out, float* __restrict__ W)
{
    __shared__ float sP[TPB * 11];            // column-partial scatter (stride 11: conflict-free)
    __shared__ __align__(16) float sTF[MN * NF];
    __shared__ float sC2[MN * MN];
    __shared__ float sq[MN], scq[MN], sqC2[MN], sv[MN], sNSQ[MN];
    __shared__ float sRed[3 * NW];
    __shared__ float sBC[2];
    __shared__ float sDots[4];

    const int tid = threadIdx.x;
    const int bid = blockIdx.x;

    unsigned* BM  = (unsigned*)(W + OFF_D);   // aliased; dead after setup
    int* rowst    = (int*)(W + OFF_RS);
    int* degi     = (int*)(W + OFF_DEG);
    int* colix    = (int*)(W + OFF_CI);
    int* nnzc     = (int*)(W + OFF_NNZ);
    float* Mw     = W + OFF_M;
    float* Tw     = W + OFF_T;
    float* Cw     = W + OFF_C;
    float* Dw     = W + OFF_D;
    float* dTw    = W + OFF_DT;

    const float alpha = 1.f / (1.f + __expf(-a0[0]));
    const float invn  = 1.f / (float)NN;
    const float alpha2 = 2.f * alpha;

    cgx::grid_group grid = cgx::this_grid();

    // ---- P0: zero bitmap + nnz counter ----
    for (int idx = bid * TPB + tid; idx < NN * WPR; idx += NBLK * TPB) BM[idx] = 0u;
    if (bid == 0 && tid == 0) *nnzc = 0;
    grid.sync();

    // ---- P1: adjacency bits (symmetrized, deduped) + feature cost M ----
    {
        const unsigned* uw = (const unsigned*)eiv;
        const bool is64 = (uw[1] == 0u && uw[3] == 0u && uw[5] == 0u);
        for (int e = bid * TPB + tid; e < NE; e += NBLK * TPB) {
            int s, d;
            if (is64) {
                s = (int)((const long long*)eiv)[e];
                d = (int)((const long long*)eiv)[NE + e];
            } else {
                s = ((const int*)eiv)[e];
                d = ((const int*)eiv)[NE + e];
            }
            atomicOr(&BM[(size_t)s * WPR + (d >> 5)], 1u << (d & 31));
            atomicOr(&BM[(size_t)d * WPR + (s >> 5)], 1u << (s & 31));
        }
        const int t = bid >> 4, rb = bid & 15;   // 16 row-blocks of 384 per template
        for (int k = tid; k < MN * NF; k += TPB) sTF[k] = tf[t * MN * NF + k];
        __syncthreads();
        if (tid < MN) {
            float s = 0.f;
            for (int k = 0; k < NF; ++k) { float v = sTF[tid * NF + k]; s += v * v; }
            sNSQ[tid] = s;
        }
        __syncthreads();
        if (tid < 384) {
            const int i = rb * 384 + tid;
            const float4* x4 = (const float4*)(x + (size_t)i * NF);
            const float4* t4 = (const float4*)sTF;
            float acc[MN]; float xn = 0.f;
            #pragma unroll
            for (int j = 0; j < MN; ++j) acc[j] = 0.f;
            for (int k4 = 0; k4 < NF / 4; ++k4) {
                float4 xv = x4[k4];
                xn += xv.x * xv.x + xv.y * xv.y + xv.z * xv.z + xv.w * xv.w;
                #pragma unroll
                for (int j = 0; j < MN; ++j) {
                    float4 tv = t4[j * (NF / 4) + k4];
                    acc[j] += xv.x * tv.x + xv.y * tv.y + xv.z * tv.z + xv.w * tv.w;
                }
            }
            float* Mrow = Mw + (size_t)t * NN * MN + (size_t)i * MN;
            #pragma unroll
            for (int j = 0; j < MN; ++j) Mrow[j] = xn + sNSQ[j] - 2.f * acc[j];
        }
    }
    grid.sync();

    // ---- P2: degrees + CSR ----
    {
        const int i = bid * TPB + tid;
        if (i < NN) {
            int cnt = 0;
            for (int w = 0; w < WPR; ++w) cnt += __popc(BM[(size_t)i * WPR + w]);
            int st = atomicAdd(nnzc, cnt);
            rowst[i] = st; degi[i] = cnt;
            int p = st;
            for (int w = 0; w < WPR; ++w) {
                unsigned m = BM[(size_t)i * WPR + w];
                while (m) { int b = __ffs(m) - 1; m &= m - 1; colix[p++] = (w << 5) + b; }
            }
        }
    }
    grid.sync();   // last grid-wide sync; CG loop is fully block-local below

    if (bid >= NT) return;

    // ================= block-local CG loop: block t owns template t =================
    const int t = bid;
    float* Mb  = Mw  + (size_t)t * NN * MN;
    float* Tb  = Tw  + (size_t)t * NN * MN;
    float* Cb  = Cw  + (size_t)t * NN * MN;
    float* Db  = Dw  + (size_t)t * NN * MN;
    float* dTb = dTw + (size_t)t * NN * STR;

    // per-template constants (softmax(q0), C2^2 q, q^T C2) + C2 tile
    if (tid == 0) {
        float qv[MN]; float qm = -1e30f;
        for (int j = 0; j < MN; ++j) { qv[j] = q0[t * MN + j]; qm = fmaxf(qm, qv[j]); }
        float qs = 0.f;
        for (int j = 0; j < MN; ++j) { qv[j] = __expf(qv[j] - qm); qs += qv[j]; }
        for (int j = 0; j < MN; ++j) { qv[j] /= qs; sq[j] = qv[j]; }
        for (int j = 0; j < MN; ++j) {
            float s2 = 0.f, s1 = 0.f;
            for (int k = 0; k < MN; ++k) {
                float cjk = tpl[t * MN * MN + j * MN + k];
                s2 += cjk * cjk * qv[k];
                s1 += tpl[t * MN * MN + k * MN + j] * qv[k];
            }
            scq[j] = s2; sqC2[j] = s1;
        }
    }
    for (int k = tid; k < MN * MN; k += TPB) sC2[k] = tpl[t * MN * MN + k];
    __syncthreads();

    for (int cgi = 0; cgi < NCG; ++cgi) {
        // ---- tau from previous iteration's dots ----
        if (tid == 0) {
            float tau = 0.f;
            if (cgi > 0) {
                float a = -2.f * alpha * sDots[3];
                float b = (1.f - alpha) * sDots[0] + alpha * (sDots[1] - 4.f * sDots[2]);
                if (a > 0.f) tau = fminf(fmaxf(-b / (2.f * a + 1e-16f), 0.f), 1.f);
                else         tau = (a + b < 0.f) ? 1.f : 0.f;
            }
            sBC[0] = tau;
        }
        __syncthreads();
        const float tau = sBC[0];

        // ---- update T,C; build grad into E (registers) ----
        float E[RPT][MN];
        float uu[RPT];
        float gmax = 0.f;
        #pragma unroll
        for (int k = 0; k < RPT; ++k) {
            const int r = tid + k * TPB;
            const float cp = (float)degi[r] * invn;
            const size_t bc = (size_t)r * MN;
            const size_t bp = (size_t)r * STR;
            float Trow[MN], Crow[MN];
            if (cgi == 0) {
                #pragma unroll
                for (int j = 0; j < MN; ++j) {
                    Trow[j] = sq[j] * invn; Crow[j] = cp * sqC2[j];
                    Tb[bc + j] = Trow[j]; Cb[bc + j] = Crow[j];
                }
            } else if (tau != 0.f) {
                #pragma unroll
                for (int j = 0; j < MN; ++j) {
                    Trow[j] = Tb[bc + j] + tau * dTb[bp + j];
                    Crow[j] = Cb[bc + j] + tau * Db[bc + j];
                    Tb[bc + j] = Trow[j]; Cb[bc + j] = Crow[j];
                }
            } else {
                #pragma unroll
                for (int j = 0; j < MN; ++j) { Trow[j] = Tb[bc + j]; Crow[j] = Cb[bc + j]; }
            }
            #pragma unroll
            for (int j = 0; j < MN; ++j) {
                float g = (1.f - alpha) * Mb[bc + j] + alpha2 * (cp + scq[j] - 2.f * Crow[j]);
                E[k][j] = g;
                gmax = fmaxf(gmax, fabsf(g));
            }
        }
        #pragma unroll
        for (int d = 32; d; d >>= 1) gmax = fmaxf(gmax, __shfl_xor(gmax, d));
        if ((tid & 63) == 0) sRed[tid >> 6] = gmax;
        __syncthreads();
        if (tid == 0) {
            float m = sRed[0];
            for (int w = 1; w < NW; ++w) m = fmaxf(m, sRed[w]);
            sBC[1] = 1.f / (0.05f * m + 1e-8f);
        }
        __syncthreads();
        const float invreg = sBC[1];
        #pragma unroll
        for (int k = 0; k < RPT; ++k)
            #pragma unroll
            for (int j = 0; j < MN; ++j)
                E[k][j] = __expf(-E[k][j] * invreg);
        #pragma unroll
        for (int k = 0; k < RPT; ++k) uu[k] = 1.f;

        // ---- exp-domain Sinkhorn (|K|<=20 by construction: reg = 5% of max|grad|) ----
        for (int it = 0; it <= NSK; ++it) {
            float acc[MN];
            #pragma unroll
            for (int j = 0; j < MN; ++j) acc[j] = 0.f;
            #pragma unroll
            for (int k = 0; k < RPT; ++k) {
                const float u = uu[k];
                #pragma unroll
                for (int j = 0; j < MN; ++j) acc[j] += E[k][j] * u;
            }
            #pragma unroll
            for (int j = 0; j < MN; ++j) sP[tid * 11 + j] = acc[j];
            __syncthreads();
            if (tid < 640) {                   // 10 cols x 64 lanes
                const int j = tid >> 6, c = tid & 63;
                float s = 0.f;
                #pragma unroll
                for (int kk = 0; kk < NW; ++kk) s += sP[(c + (kk << 6)) * 11 + j];
                #pragma unroll
                for (int d = 32; d; d >>= 1) s += __shfl_xor(s, d);
                if (c == 0) sv[j] = sq[j] / s;  // v_j = q_j / S_j
            }
            __syncthreads();
            if (it == NSK) break;               // final extra column pass
            float vv[MN];
            #pragma unroll
            for (int j = 0; j < MN; ++j) vv[j] = sv[j];
            #pragma unroll
            for (int k = 0; k < RPT; ++k) {
                float R = 0.f;
                #pragma unroll
                for (int j = 0; j < MN; ++j) R += E[k][j] * vv[j];
                uu[k] = invn * __builtin_amdgcn_rcpf(R);   // u_i = p / R_i
            }
        }

        // ---- dT = u E v - T ; write padded dT; line-search partial dots ----
        {
            float vv[MN];
            #pragma unroll
            for (int j = 0; j < MN; ++j) vv[j] = sv[j];
            float sMdT = 0.f, sCdT = 0.f, sCTdT = 0.f;
            #pragma unroll
            for (int k = 0; k < RPT; ++k) {
                const int r = tid + k * TPB;
                const float cp = (float)degi[r] * invn;
                const size_t bc = (size_t)r * MN;
                const size_t bp = (size_t)r * STR;
                float dd[MN];
                #pragma unroll
                for (int j = 0; j < MN; ++j) {
                    const float Tn = uu[k] * E[k][j] * vv[j];
                    dd[j] = Tn - Tb[bc + j];
                    sMdT  += Mb[bc + j] * dd[j];
                    sCdT  += (cp + scq[j]) * dd[j];
                    sCTdT += Cb[bc + j] * dd[j];
                }
                float4* o4 = (float4*)(dTb + bp);
                o4[0] = make_float4(dd[0], dd[1], dd[2], dd[3]);
                o4[1] = make_float4(dd[4], dd[5], dd[6], dd[7]);
                *(float2*)(dTb + bp + 8) = make_float2(dd[8], dd[9]);
            }
            #pragma unroll
            for (int d = 32; d; d >>= 1) {
                sMdT  += __shfl_xor(sMdT, d);
                sCdT  += __shfl_xor(sCdT, d);
                sCTdT += __shfl_xor(sCTdT, d);
            }
            if ((tid & 63) == 0) {
                const int w = tid >> 6;
                sRed[w] = sMdT; sRed[NW + w] = sCdT; sRed[2 * NW + w] = sCTdT;
            }
            __syncthreads();
            if (tid == 0) {
                float r0 = 0.f, r1 = 0.f, r2 = 0.f;
                for (int w = 0; w < NW; ++w) { r0 += sRed[w]; r1 += sRed[NW + w]; r2 += sRed[2 * NW + w]; }
                sDots[0] = r0; sDots[1] = r1; sDots[2] = r2;
            }
        }
        __threadfence_block();
        __syncthreads();     // dT stores drained to L2 + visible block-wide

        // ---- block-local SpMM: D = C1 @ dT @ C2 ; sA = <D, dT> ----
        {
            float dot = 0.f;
            #pragma unroll
            for (int k = 0; k < RPT; ++k) {
                const int r = tid + k * TPB;
                float y[MN];
                #pragma unroll
                for (int j = 0; j < MN; ++j) y[j] = 0.f;
                const int st = rowst[r], dg = degi[r];
                for (int e = st; e < st + dg; ++e) {
                    const int j = colix[e];
                    const float4* a4 = (const float4*)(dTb + (size_t)j * STR);
                    float4 v0 = a4[0], v1 = a4[1];
                    float2 v2 = *(const float2*)(dTb + (size_t)j * STR + 8);
                    y[0] += v0.x; y[1] += v0.y; y[2] += v0.z; y[3] += v0.w;
                    y[4] += v1.x; y[5] += v1.y; y[6] += v1.z; y[7] += v1.w;
                    y[8] += v2.x; y[9] += v2.y;
                }
                const float* dTi = dTb + (size_t)r * STR;
                float* Di = Db + (size_t)r * MN;
                #pragma unroll
                for (int c = 0; c < MN; ++c) {
                    float o = 0.f;
                    #pragma unroll
                    for (int j = 0; j < MN; ++j) o += y[j] * sC2[j * MN + c];
                    Di[c] = o;
                    dot += o * dTi[c];
                }
            }
            #pragma unroll
            for (int d = 32; d; d >>= 1) dot += __shfl_xor(dot, d);
            if ((tid & 63) == 0) sRed[tid >> 6] = dot;
            __syncthreads();
            if (tid == 0) {
                float s = 0.f;
                for (int w = 0; w < NW; ++w) s += sRed[w];
                sDots[3] = s;
            }
        }
        __syncthreads();
    }

    // ---- final tau + objective ----
    if (tid == 0) {
        float a = -2.f * alpha * sDots[3];
        float b = (1.f - alpha) * sDots[0] + alpha * (sDots[1] - 4.f * sDots[2]);
        float tau;
        if (a > 0.f) tau = fminf(fmaxf(-b / (2.f * a + 1e-16f), 0.f), 1.f);
        else         tau = (a + b < 0.f) ? 1.f : 0.f;
        sBC[0] = tau;
    }
    __syncthreads();
    {
        const float tau = sBC[0];
        float gw = 0.f, wass = 0.f;
        #pragma unroll
        for (int k = 0; k < RPT; ++k) {
            const int r = tid + k * TPB;
            const float cp = (float)degi[r] * invn;
            const size_t bc = (size_t)r * MN;
            const size_t bp = (size_t)r * STR;
            #pragma unroll
            for (int j = 0; j < MN; ++j) {
                const float Tf = Tb[bc + j] + tau * dTb[bp + j];
                const float Cf = Cb[bc + j] + tau * Db[bc + j];
                gw   += (cp + scq[j] - 2.f * Cf) * Tf;
                wass += Mb[bc + j] * Tf;
            }
        }
        #pragma unroll
        for (int d = 32; d; d >>= 1) {
            gw   += __shfl_xor(gw, d);
            wass += __shfl_xor(wass, d);
        }
        if ((tid & 63) == 0) { sRed[tid >> 6] = gw; sRed[NW + (tid >> 6)] = wass; }
        __syncthreads();
        if (tid == 0) {
            float g = 0.f, ws = 0.f;
            for (int w = 0; w < NW; ++w) { g += sRed[w]; ws += sRed[NW + w]; }
            out[t] = (1.f - alpha) * ws + alpha * g;
        }
    }
}

extern "C" void kernel_launch(void* const* d_in, const int* in_sizes, int n_in,
                              void* d_out, int out_size, void* d_ws, size_t ws_size,
                              hipStream_t stream) {
    const float* x   = (const float*)d_in[0];
    const void*  ei  = d_in[1];
    const float* tpl = (const float*)d_in[2];
    const float* tfp = (const float*)d_in[3];
    const float* q0  = (const float*)d_in[4];
    const float* a0  = (const float*)d_in[5];
    float* outp = (float*)d_out;
    float* Wp   = (float*)d_ws;
    void* args[] = { &x, &ei, &tpl, &tfp, &q0, &a0, &outp, &Wp };
    hipLaunchCooperativeKernel(reinterpret_cast<const void*>(&tfgw_kernel),
                               dim3(NBLK), dim3(TPB), args, 0, stream);
}

// Round 4
// 1930.985 us; speedup vs baseline: 1.3709x; 1.3709x over previous
//
#include <hip/hip_runtime.h>
#include <hip/hip_cooperative_groups.h>

namespace cgx = cooperative_groups;

static constexpr int NN  = 6144;
static constexpr int NE  = 98304;
static constexpr int NF  = 128;
static constexpr int NT  = 16;
static constexpr int MN  = 10;
static constexpr int NCG = 5;
static constexpr int NSK = 50;
static constexpr int WPR = NN / 32;      // 192 bitmap words per row
static constexpr int TPB = 768;
static constexpr int NBLK = 256;
static constexpr int RPT = NN / TPB;     // 8 rows/thread; E packed bf16 -> 40 VGPRs
static constexpr int NW  = TPB / 64;     // 12 waves
static constexpr size_t PT = (size_t)NN * MN;   // 61440 floats per template array

static_assert(TPB * RPT == NN, "row mapping");

// workspace layout (float elements); BM (setup-only) aliases T+C region
static constexpr size_t OFF_M   = 0;
static constexpr size_t OFF_T   = OFF_M   + PT * NT;
static constexpr size_t OFF_C   = OFF_T   + PT * NT;
static constexpr size_t OFF_D   = OFF_C   + PT * NT;
static constexpr size_t OFF_DTG = OFF_D   + PT * NT;
static constexpr size_t OFF_RS  = OFF_DTG + PT * NT;
static constexpr size_t OFF_DEG = OFF_RS  + NN;
static constexpr size_t OFF_CI  = OFF_DEG + NN;     // ushort[2*NE] packed in NE floats
static constexpr size_t OFF_NNZ = OFF_CI  + NE;
// total ~5.03M floats ~= 20.1 MB

static constexpr int LDS_DYN = NN * 24;  // 147456 B: bf16 dT rows (24B); sP(33792B) overlays

__device__ __forceinline__ unsigned f2bf(float f) {          // fp32 -> bf16 (rne)
    unsigned u = __float_as_uint(f);
    return (u + 0x7fffu + ((u >> 16) & 1u)) >> 16;
}
__device__ __forceinline__ float bflo(unsigned w) { return __uint_as_float(w << 16); }
__device__ __forceinline__ float bfhi(unsigned w) { return __uint_as_float(w & 0xffff0000u); }

extern __shared__ char sMem[];

__global__ __launch_bounds__(TPB, 3) void tfgw_kernel(
    const float* __restrict__ x, const void* __restrict__ eiv,
    const float* __restrict__ tpl, const float* __restrict__ tf,
    const float* __restrict__ q0, const float* __restrict__ a0,
    float* __restrict__ out, float* __restrict__ W)
{
    __shared__ __align__(16) float sTF[MN * NF];
    __shared__ float sC2[MN * MN];
    __shared__ float sq[MN], scq[MN], sqC2[MN], sv[MN], sNSQ[MN], sCv[MN];
    __shared__ float sRed[3 * NW];
    __shared__ float sBC[2];
    __shared__ float sDots[4];

    const int tid = threadIdx.x;
    const int bid = blockIdx.x;

    unsigned* BM   = (unsigned*)(W + OFF_T);   // aliased; dead after setup
    int* rowst     = (int*)(W + OFF_RS);
    int* degi      = (int*)(W + OFF_DEG);
    unsigned short* colix = (unsigned short*)(W + OFF_CI);
    int* nnzc      = (int*)(W + OFF_NNZ);
    float* Mw  = W + OFF_M;
    float* Tw  = W + OFF_T;
    float* Cw  = W + OFF_C;
    float* Dw  = W + OFF_D;
    float* dTg = W + OFF_DTG;

    float* sP = (float*)sMem;                  // [TPB*11] fp32, Sinkhorn partials

    const float alpha  = 1.f / (1.f + __expf(-a0[0]));
    const float invn   = 1.f / (float)NN;
    const float alpha2 = 2.f * alpha;
    const float oma    = 1.f - alpha;

    cgx::grid_group grid = cgx::this_grid();

    // ---- P0: zero bitmap + nnz ----
    for (int idx = bid * TPB + tid; idx < NN * WPR; idx += NBLK * TPB) BM[idx] = 0u;
    if (bid == 0 && tid == 0) *nnzc = 0;
    grid.sync();

    // ---- P1: adjacency bits (symmetrized, deduped) + feature cost M ----
    {
        const unsigned* uw = (const unsigned*)eiv;
        const bool is64 = (uw[1] == 0u && uw[3] == 0u && uw[5] == 0u);
        for (int e = bid * TPB + tid; e < NE; e += NBLK * TPB) {
            int s, d;
            if (is64) {
                s = (int)((const long long*)eiv)[e];
                d = (int)((const long long*)eiv)[NE + e];
            } else {
                s = ((const int*)eiv)[e];
                d = ((const int*)eiv)[NE + e];
            }
            atomicOr(&BM[(size_t)s * WPR + (d >> 5)], 1u << (d & 31));
            atomicOr(&BM[(size_t)d * WPR + (s >> 5)], 1u << (s & 31));
        }
        const int t = bid >> 4, rb = bid & 15;   // 16 row-blocks of 384 per template
        for (int k = tid; k < MN * NF; k += TPB) sTF[k] = tf[t * MN * NF + k];
        __syncthreads();
        if (tid < MN) {
            float s = 0.f;
            for (int k = 0; k < NF; ++k) { float v = sTF[tid * NF + k]; s += v * v; }
            sNSQ[tid] = s;
        }
        __syncthreads();
        if (tid < 384) {
            const int i = rb * 384 + tid;
            const float4* x4 = (const float4*)(x + (size_t)i * NF);
            const float4* t4 = (const float4*)sTF;
            float acc[MN]; float xn = 0.f;
            #pragma unroll
            for (int j = 0; j < MN; ++j) acc[j] = 0.f;
            for (int k4 = 0; k4 < NF / 4; ++k4) {
                float4 xv = x4[k4];
                xn += xv.x * xv.x + xv.y * xv.y + xv.z * xv.z + xv.w * xv.w;
                #pragma unroll
                for (int j = 0; j < MN; ++j) {
                    float4 tv = t4[j * (NF / 4) + k4];
                    acc[j] += xv.x * tv.x + xv.y * tv.y + xv.z * tv.z + xv.w * tv.w;
                }
            }
            float* Mrow = Mw + (size_t)t * PT + (size_t)i * MN;
            #pragma unroll
            for (int j = 0; j < MN; ++j) Mrow[j] = xn + sNSQ[j] - 2.f * acc[j];
        }
    }
    grid.sync();

    // ---- P2: degrees + CSR (ushort cols; row order irrelevant) ----
    {
        const int i = bid * TPB + tid;
        if (i < NN) {
            int cnt = 0;
            for (int w = 0; w < WPR; ++w) cnt += __popc(BM[(size_t)i * WPR + w]);
            int st = atomicAdd(nnzc, cnt);
            rowst[i] = st; degi[i] = cnt;
            int p = st;
            for (int w = 0; w < WPR; ++w) {
                unsigned m = BM[(size_t)i * WPR + w];
                while (m) { int b = __ffs(m) - 1; m &= m - 1; colix[p++] = (unsigned short)((w << 5) + b); }
            }
        }
    }
    grid.sync();     // last grid sync; rest is block-local

    if (bid >= NT) return;

    // ================= block t owns template t =================
    const int t = bid;
    float* Mb  = Mw  + (size_t)t * PT;
    float* Tb  = Tw  + (size_t)t * PT;
    float* Cb  = Cw  + (size_t)t * PT;
    float* Db  = Dw  + (size_t)t * PT;
    float* dTb = dTg + (size_t)t * PT;

    if (tid == 0) {
        float qv[MN]; float qm = -1e30f;
        for (int j = 0; j < MN; ++j) { qv[j] = q0[t * MN + j]; qm = fmaxf(qm, qv[j]); }
        float qs = 0.f;
        for (int j = 0; j < MN; ++j) { qv[j] = __expf(qv[j] - qm); qs += qv[j]; }
        for (int j = 0; j < MN; ++j) { qv[j] /= qs; sq[j] = qv[j]; }
        for (int j = 0; j < MN; ++j) {
            float s2 = 0.f, s1 = 0.f;
            for (int k = 0; k < MN; ++k) {
                float cjk = tpl[t * MN * MN + j * MN + k];
                s2 += cjk * cjk * qv[k];
                s1 += tpl[t * MN * MN + k * MN + j] * qv[k];
            }
            scq[j] = s2; sqC2[j] = s1;
        }
    }
    for (int k = tid; k < MN * MN; k += TPB) sC2[k] = tpl[t * MN * MN + k];
    __syncthreads();

    unsigned Ep[RPT * 5];   // packed bf16: row k in Ep[5k..5k+4] (E, later dT)
    float uu[RPT];

    for (int cgi = 0; cgi < NCG; ++cgi) {
        // ---- tau ----
        if (tid == 0) {
            float tau = 0.f;
            if (cgi > 0) {
                float a = -2.f * alpha * sDots[3];
                float b = oma * sDots[0] + alpha * (sDots[1] - 4.f * sDots[2]);
                if (a > 0.f) tau = fminf(fmaxf(-b / (2.f * a + 1e-16f), 0.f), 1.f);
                else         tau = (a + b < 0.f) ? 1.f : 0.f;
            }
            sBC[0] = tau;
        }
        __syncthreads();
        const float tau = sBC[0];

        // ---- Phase A: T,C update + gmax ----
        float gmax = 0.f;
        #pragma unroll
        for (int k = 0; k < RPT; ++k) {
            const int r = tid + k * TPB;
            const float cp = (float)degi[r] * invn;
            const size_t bc = (size_t)r * MN;
            float Trow[MN], Crow[MN];
            if (cgi == 0) {
                #pragma unroll
                for (int j = 0; j < MN; ++j) { Trow[j] = sq[j] * invn; Crow[j] = cp * sqC2[j]; }
                #pragma unroll
                for (int h = 0; h < 5; ++h) {
                    *(float2*)(Tb + bc + 2 * h) = make_float2(Trow[2*h], Trow[2*h+1]);
                    *(float2*)(Cb + bc + 2 * h) = make_float2(Crow[2*h], Crow[2*h+1]);
                }
            } else if (tau != 0.f) {
                #pragma unroll
                for (int h = 0; h < 5; ++h) {
                    float2 tv = *(const float2*)(Tb  + bc + 2*h);
                    float2 dv = *(const float2*)(dTb + bc + 2*h);
                    float2 cv = *(const float2*)(Cb  + bc + 2*h);
                    float2 Dv = *(const float2*)(Db  + bc + 2*h);
                    Trow[2*h]   = tv.x + tau * dv.x;  Trow[2*h+1] = tv.y + tau * dv.y;
                    Crow[2*h]   = cv.x + tau * Dv.x;  Crow[2*h+1] = cv.y + tau * Dv.y;
                    *(float2*)(Tb + bc + 2*h) = make_float2(Trow[2*h], Trow[2*h+1]);
                    *(float2*)(Cb + bc + 2*h) = make_float2(Crow[2*h], Crow[2*h+1]);
                }
            } else {
                #pragma unroll
                for (int h = 0; h < 5; ++h) {
                    float2 cv = *(const float2*)(Cb + bc + 2*h);
                    Crow[2*h] = cv.x; Crow[2*h+1] = cv.y;
                }
            }
            #pragma unroll
            for (int h = 0; h < 5; ++h) {
                float2 mv = *(const float2*)(Mb + bc + 2*h);
                float g0 = oma * mv.x + alpha2 * (cp + scq[2*h]   - 2.f * Crow[2*h]);
                float g1 = oma * mv.y + alpha2 * (cp + scq[2*h+1] - 2.f * Crow[2*h+1]);
                gmax = fmaxf(gmax, fmaxf(fabsf(g0), fabsf(g1)));
            }
        }
        #pragma unroll
        for (int d = 32; d; d >>= 1) gmax = fmaxf(gmax, __shfl_xor(gmax, d));
        if ((tid & 63) == 0) sRed[tid >> 6] = gmax;
        __syncthreads();
        if (tid == 0) {
            float m = sRed[0];
            for (int w = 1; w < NW; ++w) m = fmaxf(m, sRed[w]);
            sBC[1] = 1.f / (0.05f * m + 1e-8f);
        }
        __syncthreads();
        const float invreg = sBC[1];

        // ---- Phase B: recompute g, E = exp(-g/reg), pack bf16 into Ep ----
        #pragma unroll
        for (int k = 0; k < RPT; ++k) {
            const int r = tid + k * TPB;
            const float cp = (float)degi[r] * invn;
            const size_t bc = (size_t)r * MN;
            #pragma unroll
            for (int h = 0; h < 5; ++h) {
                float2 mv = *(const float2*)(Mb + bc + 2*h);
                float2 cv = *(const float2*)(Cb + bc + 2*h);
                float g0 = oma * mv.x + alpha2 * (cp + scq[2*h]   - 2.f * cv.x);
                float g1 = oma * mv.y + alpha2 * (cp + scq[2*h+1] - 2.f * cv.y);
                float e0 = __expf(-g0 * invreg);
                float e1 = __expf(-g1 * invreg);
                Ep[5*k + h] = f2bf(e0) | (f2bf(e1) << 16);
            }
        }

        // ---- Sinkhorn: v, then fused (u,v) x50, early-exit on v convergence ----
        {   // iter 0: u = 1
            float acc[MN];
            #pragma unroll
            for (int j = 0; j < MN; ++j) acc[j] = 0.f;
            #pragma unroll
            for (int k = 0; k < RPT; ++k)
                #pragma unroll
                for (int h = 0; h < 5; ++h) {
                    unsigned w = Ep[5*k + h];
                    acc[2*h] += bflo(w); acc[2*h+1] += bfhi(w);
                }
            #pragma unroll
            for (int j = 0; j < MN; ++j) sP[tid * 11 + j] = acc[j];
            __syncthreads();
            if (tid < 640) {
                const int j = tid >> 6, c = tid & 63;
                float s = 0.f;
                #pragma unroll
                for (int kk = 0; kk < NW; ++kk) s += sP[(c + (kk << 6)) * 11 + j];
                #pragma unroll
                for (int d = 32; d; d >>= 1) s += __shfl_xor(s, d);
                if (c == 0) { sv[j] = sq[j] / s; sCv[j] = 0.f; }
            }
            __syncthreads();
        }
        for (int it = 1; it <= NSK; ++it) {
            float vv[MN];
            #pragma unroll
            for (int j = 0; j < MN; ++j) vv[j] = sv[j];
            float acc[MN];
            #pragma unroll
            for (int j = 0; j < MN; ++j) acc[j] = 0.f;
            #pragma unroll
            for (int k = 0; k < RPT; ++k) {
                float ev[MN];
                #pragma unroll
                for (int h = 0; h < 5; ++h) {
                    unsigned w = Ep[5*k + h];
                    ev[2*h] = bflo(w); ev[2*h+1] = bfhi(w);
                }
                float R = 0.f;
                #pragma unroll
                for (int j = 0; j < MN; ++j) R += ev[j] * vv[j];
                const float u = invn * __builtin_amdgcn_rcpf(R);
                uu[k] = u;
                #pragma unroll
                for (int j = 0; j < MN; ++j) acc[j] += ev[j] * u;
            }
            #pragma unroll
            for (int j = 0; j < MN; ++j) sP[tid * 11 + j] = acc[j];
            __syncthreads();
            if (tid < 640) {
                const int j = tid >> 6, c = tid & 63;
                float s = 0.f;
                #pragma unroll
                for (int kk = 0; kk < NW; ++kk) s += sP[(c + (kk << 6)) * 11 + j];
                #pragma unroll
                for (int d = 32; d; d >>= 1) s += __shfl_xor(s, d);
                if (c == 0) {
                    float vold = sv[j];
                    float vnew = sq[j] / s;
                    sCv[j] = (fabsf(vnew - vold) <= 3e-6f * vnew) ? 1.f : 0.f;
                    sv[j] = vnew;
                }
            }
            __syncthreads();
            float cs = 0.f;
            #pragma unroll
            for (int j = 0; j < MN; ++j) cs += sCv[j];
            if (cs == 10.f) break;     // fixed point reached; rest are no-ops
        }

        // ---- (a) dT = uEv - T: dots, write fp32 dT, repack dd->Ep ----
        {
            float vv[MN];
            #pragma unroll
            for (int j = 0; j < MN; ++j) vv[j] = sv[j];
            float sMdT = 0.f, sCdT = 0.f, sCTdT = 0.f;
            #pragma unroll
            for (int k = 0; k < RPT; ++k) {
                const int r = tid + k * TPB;
                const float cp = (float)degi[r] * invn;
                const size_t bc = (size_t)r * MN;
                const float u = uu[k];
                float dd[MN];
                #pragma unroll
                for (int h = 0; h < 5; ++h) {
                    unsigned w = Ep[5*k + h];
                    float2 tv = *(const float2*)(Tb + bc + 2*h);
                    float2 mv = *(const float2*)(Mb + bc + 2*h);
                    float2 cv = *(const float2*)(Cb + bc + 2*h);
                    float d0 = u * bflo(w) * vv[2*h]   - tv.x;
                    float d1 = u * bfhi(w) * vv[2*h+1] - tv.y;
                    dd[2*h] = d0; dd[2*h+1] = d1;
                    sMdT  += mv.x * d0 + mv.y * d1;
                    sCdT  += (cp + scq[2*h]) * d0 + (cp + scq[2*h+1]) * d1;
                    sCTdT += cv.x * d0 + cv.y * d1;
                    *(float2*)(dTb + bc + 2*h) = make_float2(d0, d1);
                }
                #pragma unroll
                for (int h = 0; h < 5; ++h)
                    Ep[5*k + h] = f2bf(dd[2*h]) | (f2bf(dd[2*h+1]) << 16);
            }
            #pragma unroll
            for (int d = 32; d; d >>= 1) {
                sMdT  += __shfl_xor(sMdT, d);
                sCdT  += __shfl_xor(sCdT, d);
                sCTdT += __shfl_xor(sCTdT, d);
            }
            if ((tid & 63) == 0) {
                const int w = tid >> 6;
                sRed[w] = sMdT; sRed[NW + w] = sCdT; sRed[2*NW + w] = sCTdT;
            }
            __syncthreads();   // also: everyone done reading Ep-as-E & sP region
            if (tid == 0) {
                float r0 = 0.f, r1 = 0.f, r2 = 0.f;
                for (int w = 0; w < NW; ++w) { r0 += sRed[w]; r1 += sRed[NW+w]; r2 += sRed[2*NW+w]; }
                sDots[0] = r0; sDots[1] = r1; sDots[2] = r2;
            }
        }

        // ---- (b) stage bf16 dT rows into LDS (24B rows, 8B-aligned) ----
        #pragma unroll
        for (int k = 0; k < RPT; ++k) {
            const int r = tid + k * TPB;
            char* rb = sMem + 24 * (size_t)r;
            *(uint2*)rb        = make_uint2(Ep[5*k],   Ep[5*k+1]);
            *(uint2*)(rb + 8)  = make_uint2(Ep[5*k+2], Ep[5*k+3]);
            *(unsigned*)(rb + 16) = Ep[5*k+4];
        }
        __syncthreads();

        // ---- (c) SpMM gather from LDS: D = C1 dT C2, sA = <D,dT> ----
        {
            float dot = 0.f;
            #pragma unroll
            for (int k = 0; k < RPT; ++k) {
                const int r = tid + k * TPB;
                float y[MN];
                #pragma unroll
                for (int j = 0; j < MN; ++j) y[j] = 0.f;
                const int st = rowst[r], dg = degi[r];
                for (int e = st; e < st + dg; ++e) {
                    const int j = colix[e];
                    const char* rb = sMem + 24 * (size_t)j;
                    uint2 a = *(const uint2*)rb;
                    uint2 b = *(const uint2*)(rb + 8);
                    unsigned c4 = *(const unsigned*)(rb + 16);
                    y[0] += bflo(a.x); y[1] += bfhi(a.x);
                    y[2] += bflo(a.y); y[3] += bfhi(a.y);
                    y[4] += bflo(b.x); y[5] += bfhi(b.x);
                    y[6] += bflo(b.y); y[7] += bfhi(b.y);
                    y[8] += bflo(c4);  y[9] += bfhi(c4);
                }
                const size_t bc = (size_t)r * MN;
                float ddk[MN];
                #pragma unroll
                for (int h = 0; h < 5; ++h) {
                    unsigned w = Ep[5*k + h];
                    ddk[2*h] = bflo(w); ddk[2*h+1] = bfhi(w);
                }
                #pragma unroll
                for (int h = 0; h < 5; ++h) {
                    float o0 = 0.f, o1 = 0.f;
                    #pragma unroll
                    for (int j = 0; j < MN; ++j) {
                        o0 += y[j] * sC2[j * MN + 2*h];
                        o1 += y[j] * sC2[j * MN + 2*h + 1];
                    }
                    *(float2*)(Db + bc + 2*h) = make_float2(o0, o1);
                    dot += o0 * ddk[2*h] + o1 * ddk[2*h+1];
                }
            }
            #pragma unroll
            for (int d = 32; d; d >>= 1) dot += __shfl_xor(dot, d);
            if ((tid & 63) == 0) sRed[tid >> 6] = dot;
            __syncthreads();
            if (tid == 0) {
                float s = 0.f;
                for (int w = 0; w < NW; ++w) s += sRed[w];
                sDots[3] = s;
            }
            __syncthreads();
        }
    }

    // ---- final tau + objective ----
    if (tid == 0) {
        float a = -2.f * alpha * sDots[3];
        float b = oma * sDots[0] + alpha * (sDots[1] - 4.f * sDots[2]);
        float tau;
        if (a > 0.f) tau = fminf(fmaxf(-b / (2.f * a + 1e-16f), 0.f), 1.f);
        else         tau = (a + b < 0.f) ? 1.f : 0.f;
        sBC[0] = tau;
    }
    __syncthreads();
    {
        const float tau = sBC[0];
        float gw = 0.f, wass = 0.f;
        #pragma unroll
        for (int k = 0; k < RPT; ++k) {
            const int r = tid + k * TPB;
            const float cp = (float)degi[r] * invn;
            const size_t bc = (size_t)r * MN;
            #pragma unroll
            for (int h = 0; h < 5; ++h) {
                float2 tv = *(const float2*)(Tb  + bc + 2*h);
                float2 dv = *(const float2*)(dTb + bc + 2*h);
                float2 cv = *(const float2*)(Cb  + bc + 2*h);
                float2 Dv = *(const float2*)(Db  + bc + 2*h);
                float2 mv = *(const float2*)(Mb  + bc + 2*h);
                float Tf0 = tv.x + tau * dv.x, Tf1 = tv.y + tau * dv.y;
                float Cf0 = cv.x + tau * Dv.x, Cf1 = cv.y + tau * Dv.y;
                gw   += (cp + scq[2*h]   - 2.f * Cf0) * Tf0
                      + (cp + scq[2*h+1] - 2.f * Cf1) * Tf1;
                wass += mv.x * Tf0 + mv.y * Tf1;
            }
        }
        #pragma unroll
        for (int d = 32; d; d >>= 1) {
            gw   += __shfl_xor(gw, d);
            wass += __shfl_xor(wass, d);
        }
        if ((tid & 63) == 0) { sRed[tid >> 6] = gw; sRed[NW + (tid >> 6)] = wass; }
        __syncthreads();
        if (tid == 0) {
            float g = 0.f, ws = 0.f;
            for (int w = 0; w < NW; ++w) { g += sRed[w]; ws += sRed[NW + w]; }
            out[t] = oma * ws + alpha * g;
        }
    }
}

extern "C" void kernel_launch(void* const* d_in, const int* in_sizes, int n_in,
                              void* d_out, int out_size, void* d_ws, size_t ws_size,
                              hipStream_t stream) {
    const float* x   = (const float*)d_in[0];
    const void*  ei  = d_in[1];
    const float* tpl = (const float*)d_in[2];
    const float* tfp = (const float*)d_in[3];
    const float* q0  = (const float*)d_in[4];
    const float* a0  = (const float*)d_in[5];
    float* outp = (float*)d_out;
    float* Wp   = (float*)d_ws;
    // allow >64KB dynamic LDS (idempotent host-side attribute; not a stream op)
    (void)hipFuncSetAttribute(reinterpret_cast<const void*>(&tfgw_kernel),
                              hipFuncAttributeMaxDynamicSharedMemorySize, LDS_DYN);
    void* args[] = { &x, &ei, &tpl, &tfp, &q0, &a0, &outp, &Wp };
    hipLaunchCooperativeKernel(reinterpret_cast<const void*>(&tfgw_kernel),
                               dim3(NBLK), dim3(TPB), args, LDS_DYN, stream);
}

// Round 6
// 1413.414 us; speedup vs baseline: 1.8729x; 1.3662x over previous
//
#include <hip/hip_runtime.h>
#include <hip/hip_cooperative_groups.h>

namespace cgx = cooperative_groups;

static constexpr int NN  = 6144;
static constexpr int NE  = 98304;
static constexpr int NF  = 128;
static constexpr int NT  = 16;
static constexpr int MN  = 10;
static constexpr int NCG = 5;
static constexpr int NSK = 50;
static constexpr int WPR = NN / 32;
static constexpr int TPB = 768;
static constexpr int NBLK = 256;
static constexpr int RPT = NN / TPB;   // 8 rows/thread
static constexpr int NW  = TPB / 64;   // 12 waves

static_assert(TPB * RPT == NN, "row mapping");

// workspace layout (float elements); BM (setup-only) aliases T+C region
static constexpr size_t OFF_M   = 0;
static constexpr size_t OFF_T   = OFF_M  + (size_t)NT * NN * MN;
static constexpr size_t OFF_C   = OFF_T  + (size_t)NT * NN * MN;
static constexpr size_t OFF_DT  = OFF_C  + (size_t)NT * NN * MN;  // u32 bf16-pairs [NT][NN][5]
static constexpr size_t OFF_D   = OFF_DT + (size_t)NT * NN * 5;   // u32 bf16-pairs [NT][NN][5]
static constexpr size_t OFF_RS  = OFF_D  + (size_t)NT * NN * 5;
static constexpr size_t OFF_DEG = OFF_RS + NN;
static constexpr size_t OFF_CI  = OFF_DEG + NN;                   // ushort[2*NE] in NE floats
static constexpr size_t OFF_NNZ = OFF_CI + NE;
// total ~4.04M floats ~= 16.2 MB

static constexpr int LDS_E   = NN * 5 * 4;     // 122880 B: 5 planes of bf16-pair dwords
static constexpr int LDS_SP  = TPB * 11 * 4;   // 33792 B: reduction scatter (stride 11)
static constexpr int LDS_DYN = LDS_E + LDS_SP; // 156672 B

__device__ __forceinline__ unsigned f2bf(float f) {            // fp32 -> bf16 (rne)
    unsigned u = __float_as_uint(f);
    return (u + 0x7fffu + ((u >> 16) & 1u)) >> 16;
}
__device__ __forceinline__ unsigned packbf(float a, float b) { return f2bf(a) | (f2bf(b) << 16); }
__device__ __forceinline__ float bflo(unsigned w) { return __uint_as_float(w << 16); }
__device__ __forceinline__ float bfhi(unsigned w) { return __uint_as_float(w & 0xffff0000u); }

extern __shared__ char sMem[];

__global__ __launch_bounds__(TPB) void tfgw_kernel(
    const float* __restrict__ x, const void* __restrict__ eiv,
    const float* __restrict__ tpl, const float* __restrict__ tf,
    const float* __restrict__ q0, const float* __restrict__ a0,
    float* __restrict__ out, float* __restrict__ W)
{
    __shared__ float sC2[MN * MN];
    __shared__ float sq[MN], scq[MN], sqC2[MN], sv[MN], sCv[MN], sNSQ[MN];
    __shared__ float sRed[3 * NW];
    __shared__ float sBC[2];
    __shared__ float sDots[4];

    const int tid = threadIdx.x;
    const int bid = blockIdx.x;

    unsigned* BM    = (unsigned*)(W + OFF_T);   // aliased; dead after setup
    int* rowst      = (int*)(W + OFF_RS);
    int* degi       = (int*)(W + OFF_DEG);
    unsigned short* colix = (unsigned short*)(W + OFF_CI);
    int* nnzc       = (int*)(W + OFF_NNZ);
    float* Mw  = W + OFF_M;
    float* Tw  = W + OFF_T;
    float* Cw  = W + OFF_C;
    unsigned* dTg = (unsigned*)(W + OFF_DT);
    unsigned* Dg  = (unsigned*)(W + OFF_D);

    unsigned* PL = (unsigned*)sMem;             // planes: PL[h*NN + r]
    float* sP    = (float*)(sMem + LDS_E);      // [TPB*11]

    const float alpha  = 1.f / (1.f + __expf(-a0[0]));
    const float invn   = 1.f / (float)NN;
    const float alpha2 = 2.f * alpha;
    const float oma    = 1.f - alpha;

    cgx::grid_group grid = cgx::this_grid();

    // ---- P0: zero bitmap + nnz ----
    for (int idx = bid * TPB + tid; idx < NN * WPR; idx += NBLK * TPB) BM[idx] = 0u;
    if (bid == 0 && tid == 0) *nnzc = 0;
    grid.sync();

    // ---- P1: adjacency bits + feature cost M (sTF overlays sMem) ----
    {
        const unsigned* uw = (const unsigned*)eiv;
        const bool is64 = (uw[1] == 0u && uw[3] == 0u && uw[5] == 0u);
        for (int e = bid * TPB + tid; e < NE; e += NBLK * TPB) {
            int s, d;
            if (is64) {
                s = (int)((const long long*)eiv)[e];
                d = (int)((const long long*)eiv)[NE + e];
            } else {
                s = ((const int*)eiv)[e];
                d = ((const int*)eiv)[NE + e];
            }
            atomicOr(&BM[(size_t)s * WPR + (d >> 5)], 1u << (d & 31));
            atomicOr(&BM[(size_t)d * WPR + (s >> 5)], 1u << (s & 31));
        }
        float* sTF = (float*)sMem;
        const int t = bid >> 4, rb = bid & 15;   // 16 row-blocks of 384 per template
        for (int k = tid; k < MN * NF; k += TPB) sTF[k] = tf[t * MN * NF + k];
        __syncthreads();
        if (tid < MN) {
            float s = 0.f;
            for (int k = 0; k < NF; ++k) { float v = sTF[tid * NF + k]; s += v * v; }
            sNSQ[tid] = s;
        }
        __syncthreads();
        if (tid < 384) {
            const int i = rb * 384 + tid;
            const float4* x4 = (const float4*)(x + (size_t)i * NF);
            const float4* t4 = (const float4*)sTF;
            float acc[MN]; float xn = 0.f;
            #pragma unroll
            for (int j = 0; j < MN; ++j) acc[j] = 0.f;
            for (int k4 = 0; k4 < NF / 4; ++k4) {
                float4 xv = x4[k4];
                xn += xv.x * xv.x + xv.y * xv.y + xv.z * xv.z + xv.w * xv.w;
                #pragma unroll
                for (int j = 0; j < MN; ++j) {
                    float4 tv = t4[j * (NF / 4) + k4];
                    acc[j] += xv.x * tv.x + xv.y * tv.y + xv.z * tv.z + xv.w * tv.w;
                }
            }
            float* Mrow = Mw + (size_t)t * NN * MN + (size_t)i * MN;
            #pragma unroll
            for (int j = 0; j < MN; ++j) Mrow[j] = xn + sNSQ[j] - 2.f * acc[j];
        }
    }
    grid.sync();

    // ---- P2: degrees + CSR (ushort cols) ----
    {
        const int i = bid * TPB + tid;
        if (i < NN) {
            int cnt = 0;
            for (int w = 0; w < WPR; ++w) cnt += __popc(BM[(size_t)i * WPR + w]);
            int st = atomicAdd(nnzc, cnt);
            rowst[i] = st; degi[i] = cnt;
            int p = st;
            for (int w = 0; w < WPR; ++w) {
                unsigned m = BM[(size_t)i * WPR + w];
                while (m) { int b = __ffs(m) - 1; m &= m - 1; colix[p++] = (unsigned short)((w << 5) + b); }
            }
        }
    }
    grid.sync();     // last grid sync

    if (bid >= NT) return;

    // ================= block t owns template t =================
    const int t = bid;
    float* Mb = Mw + (size_t)t * NN * MN;
    float* Tb = Tw + (size_t)t * NN * MN;
    float* Cb = Cw + (size_t)t * NN * MN;
    unsigned* dTb = dTg + (size_t)t * NN * 5;
    unsigned* Db  = Dg  + (size_t)t * NN * 5;

    if (tid == 0) {
        float qv[MN]; float qm = -1e30f;
        for (int j = 0; j < MN; ++j) { qv[j] = q0[t * MN + j]; qm = fmaxf(qm, qv[j]); }
        float qs = 0.f;
        for (int j = 0; j < MN; ++j) { qv[j] = __expf(qv[j] - qm); qs += qv[j]; }
        for (int j = 0; j < MN; ++j) { qv[j] /= qs; sq[j] = qv[j]; }
        for (int j = 0; j < MN; ++j) {
            float s2 = 0.f, s1 = 0.f;
            for (int k = 0; k < MN; ++k) {
                float cjk = tpl[t * MN * MN + j * MN + k];
                s2 += cjk * cjk * qv[k];
                s1 += tpl[t * MN * MN + k * MN + j] * qv[k];
            }
            scq[j] = s2; sqC2[j] = s1;
        }
    }
    for (int k = tid; k < MN * MN; k += TPB) sC2[k] = tpl[t * MN * MN + k];
    __syncthreads();

    float uu[RPT];

    for (int cgi = 0; cgi < NCG; ++cgi) {
        // ---- tau from previous dots ----
        if (tid == 0) {
            float tau = 0.f;
            if (cgi > 0) {
                float a = -2.f * alpha * sDots[3];
                float b = oma * sDots[0] + alpha * (sDots[1] - 4.f * sDots[2]);
                if (a > 0.f) tau = fminf(fmaxf(-b / (2.f * a + 1e-16f), 0.f), 1.f);
                else         tau = (a + b < 0.f) ? 1.f : 0.f;
            }
            sBC[0] = tau;
        }
        __syncthreads();
        const float tau = sBC[0];

        // ---- Phase A: update T,C (cgi>0), compute gmax ----
        float gmax = 0.f;
        #pragma unroll
        for (int k = 0; k < RPT; ++k) {
            const int r = tid + k * TPB;
            const float cp = (float)degi[r] * invn;
            const size_t bc = (size_t)r * MN;
            float Crow[MN];
            if (cgi == 0) {
                #pragma unroll
                for (int j = 0; j < MN; ++j) Crow[j] = cp * sqC2[j];
            } else if (tau != 0.f) {
                const size_t b5 = (size_t)r * 5;
                #pragma unroll
                for (int h = 0; h < 5; ++h) {
                    float2 tv = *(const float2*)(Tb + bc + 2*h);
                    float2 cv = *(const float2*)(Cb + bc + 2*h);
                    unsigned dw = dTb[b5 + h], Dw_ = Db[b5 + h];
                    float T0 = tv.x + tau * bflo(dw), T1 = tv.y + tau * bfhi(dw);
                    float C0 = cv.x + tau * bflo(Dw_), C1v = cv.y + tau * bfhi(Dw_);
                    *(float2*)(Tb + bc + 2*h) = make_float2(T0, T1);
                    *(float2*)(Cb + bc + 2*h) = make_float2(C0, C1v);
                    Crow[2*h] = C0; Crow[2*h+1] = C1v;
                }
            } else {
                #pragma unroll
                for (int h = 0; h < 5; ++h) {
                    float2 cv = *(const float2*)(Cb + bc + 2*h);
                    Crow[2*h] = cv.x; Crow[2*h+1] = cv.y;
                }
            }
            #pragma unroll
            for (int h = 0; h < 5; ++h) {
                float2 mv = *(const float2*)(Mb + bc + 2*h);
                float g0 = oma * mv.x + alpha2 * (cp + scq[2*h]   - 2.f * Crow[2*h]);
                float g1 = oma * mv.y + alpha2 * (cp + scq[2*h+1] - 2.f * Crow[2*h+1]);
                gmax = fmaxf(gmax, fmaxf(__builtin_fabsf(g0), __builtin_fabsf(g1)));
            }
        }
        #pragma unroll
        for (int d = 32; d; d >>= 1) gmax = fmaxf(gmax, __shfl_xor(gmax, d));
        if ((tid & 63) == 0) sRed[tid >> 6] = gmax;
        __syncthreads();
        if (tid == 0) {
            float m = sRed[0];
            for (int w = 1; w < NW; ++w) m = fmaxf(m, sRed[w]);
            sBC[1] = 1.f / (0.05f * m + 1e-8f);
        }
        __syncthreads();
        const float invreg = sBC[1];

        // ---- Phase B: E = exp(-g*invreg) -> LDS planes (bf16 pairs) ----
        #pragma unroll
        for (int k = 0; k < RPT; ++k) {
            const int r = tid + k * TPB;
            const float cp = (float)degi[r] * invn;
            const size_t bc = (size_t)r * MN;
            #pragma unroll
            for (int h = 0; h < 5; ++h) {
                float C0, C1v;
                if (cgi == 0) { C0 = cp * sqC2[2*h]; C1v = cp * sqC2[2*h+1]; }
                else { float2 cv = *(const float2*)(Cb + bc + 2*h); C0 = cv.x; C1v = cv.y; }
                float2 mv = *(const float2*)(Mb + bc + 2*h);
                float g0 = oma * mv.x + alpha2 * (cp + scq[2*h]   - 2.f * C0);
                float g1 = oma * mv.y + alpha2 * (cp + scq[2*h+1] - 2.f * C1v);
                PL[h * NN + r] = packbf(__expf(-g0 * invreg), __expf(-g1 * invreg));
            }
        }
        __syncthreads();

        // ---- Sinkhorn iter 0 (u = 1) ----
        {
            float a[MN];
            #pragma unroll
            for (int j = 0; j < MN; ++j) a[j] = 0.f;
            #pragma unroll
            for (int k = 0; k < RPT; ++k) {
                const int r = tid + k * TPB;
                #pragma unroll
                for (int h = 0; h < 5; ++h) {
                    unsigned w = PL[h * NN + r];
                    a[2*h] += bflo(w); a[2*h+1] += bfhi(w);
                }
            }
            #pragma unroll
            for (int j = 0; j < MN; ++j) sP[tid * 11 + j] = a[j];
            __syncthreads();
            if (tid < 640) {
                const int j = tid >> 6, c = tid & 63;
                float s = 0.f;
                #pragma unroll
                for (int kk = 0; kk < NW; ++kk) s += sP[(c + (kk << 6)) * 11 + j];
                #pragma unroll
                for (int d = 32; d; d >>= 1) s += __shfl_xor(s, d);
                if (c == 0) { sv[j] = sq[j] / s; sCv[j] = 0.f; }
            }
            __syncthreads();
        }

        // ---- Sinkhorn fused (u,v) x50, early exit on v fixed point ----
        for (int it = 1; it <= NSK; ++it) {
            float vv[MN];
            #pragma unroll
            for (int j = 0; j < MN; ++j) vv[j] = sv[j];
            float a[MN];
            #pragma unroll
            for (int j = 0; j < MN; ++j) a[j] = 0.f;
            #pragma unroll
            for (int k = 0; k < RPT; ++k) {
                const int r = tid + k * TPB;
                float e[MN];
                #pragma unroll
                for (int h = 0; h < 5; ++h) {
                    unsigned w = PL[h * NN + r];
                    e[2*h] = bflo(w); e[2*h+1] = bfhi(w);
                }
                float R = 0.f;
                #pragma unroll
                for (int j = 0; j < MN; ++j) R += e[j] * vv[j];
                const float u = invn * __builtin_amdgcn_rcpf(R);
                uu[k] = u;
                #pragma unroll
                for (int j = 0; j < MN; ++j) a[j] += e[j] * u;
            }
            #pragma unroll
            for (int j = 0; j < MN; ++j) sP[tid * 11 + j] = a[j];
            __syncthreads();
            if (tid < 640) {
                const int j = tid >> 6, c = tid & 63;
                float s = 0.f;
                #pragma unroll
                for (int kk = 0; kk < NW; ++kk) s += sP[(c + (kk << 6)) * 11 + j];
                #pragma unroll
                for (int d = 32; d; d >>= 1) s += __shfl_xor(s, d);
                if (c == 0) {
                    float vold = sv[j];
                    float vnew = sq[j] / s;
                    sCv[j] = (__builtin_fabsf(vnew - vold) <= 3e-6f * vnew) ? 1.f : 0.f;
                    sv[j] = vnew;
                }
            }
            __syncthreads();
            float cs = 0.f;
            #pragma unroll
            for (int j = 0; j < MN; ++j) cs += sCv[j];
            if (cs == 10.f) break;
        }

        // ---- dT phase: dd = u*E*v - T; dots; planes <- dd(bf16); global stores ----
        {
            float vv[MN];
            #pragma unroll
            for (int j = 0; j < MN; ++j) vv[j] = sv[j];
            float sMdT = 0.f, sCdT = 0.f, sCTdT = 0.f;
            #pragma unroll
            for (int k = 0; k < RPT; ++k) {
                const int r = tid + k * TPB;
                const float cp = (float)degi[r] * invn;
                const size_t bc = (size_t)r * MN;
                const float u = uu[k];
                #pragma unroll
                for (int h = 0; h < 5; ++h) {
                    unsigned w = PL[h * NN + r];
                    float T0, T1, C0, C1v;
                    if (cgi == 0) {
                        T0 = sq[2*h] * invn;   T1 = sq[2*h+1] * invn;
                        C0 = cp * sqC2[2*h];   C1v = cp * sqC2[2*h+1];
                        // FIX(R5): initialize global T,C — Phase A at cgi==1 reads them
                        *(float2*)(Tb + bc + 2*h) = make_float2(T0, T1);
                        *(float2*)(Cb + bc + 2*h) = make_float2(C0, C1v);
                    } else {
                        float2 tv = *(const float2*)(Tb + bc + 2*h);
                        float2 cv = *(const float2*)(Cb + bc + 2*h);
                        T0 = tv.x; T1 = tv.y; C0 = cv.x; C1v = cv.y;
                    }
                    float2 mv = *(const float2*)(Mb + bc + 2*h);
                    float d0 = u * bflo(w) * vv[2*h]   - T0;
                    float d1 = u * bfhi(w) * vv[2*h+1] - T1;
                    sMdT  += mv.x * d0 + mv.y * d1;
                    sCdT  += (cp + scq[2*h]) * d0 + (cp + scq[2*h+1]) * d1;
                    sCTdT += C0 * d0 + C1v * d1;
                    unsigned pw = packbf(d0, d1);
                    PL[h * NN + r] = pw;
                    if (cgi < NCG - 1) dTb[(size_t)r * 5 + h] = pw;
                }
            }
            #pragma unroll
            for (int d = 32; d; d >>= 1) {
                sMdT  += __shfl_xor(sMdT, d);
                sCdT  += __shfl_xor(sCdT, d);
                sCTdT += __shfl_xor(sCTdT, d);
            }
            if ((tid & 63) == 0) {
                const int w = tid >> 6;
                sRed[w] = sMdT; sRed[NW + w] = sCdT; sRed[2*NW + w] = sCTdT;
            }
            __syncthreads();   // dots staged AND dd planes visible block-wide
            if (tid == 0) {
                float r0 = 0.f, r1 = 0.f, r2 = 0.f;
                for (int w = 0; w < NW; ++w) { r0 += sRed[w]; r1 += sRed[NW+w]; r2 += sRed[2*NW+w]; }
                sDots[0] = r0; sDots[1] = r1; sDots[2] = r2;
            }
        }

        // ---- SpMM: D = C1 dT C2 (gather dd planes), sA = <D,dd>; Dg store bf16 ----
        {
            float dot = 0.f;
            #pragma unroll
            for (int k = 0; k < RPT; ++k) {
                const int r = tid + k * TPB;
                float y[MN];
                #pragma unroll
                for (int j = 0; j < MN; ++j) y[j] = 0.f;
                const int st = rowst[r], dg = degi[r];
                const unsigned short* cl = colix + st;
                for (int e = 0; e < dg; ++e) {
                    const int j = cl[e];
                    unsigned w0 = PL[0 * NN + j], w1 = PL[1 * NN + j], w2 = PL[2 * NN + j];
                    unsigned w3 = PL[3 * NN + j], w4 = PL[4 * NN + j];
                    y[0] += bflo(w0); y[1] += bfhi(w0);
                    y[2] += bflo(w1); y[3] += bfhi(w1);
                    y[4] += bflo(w2); y[5] += bfhi(w2);
                    y[6] += bflo(w3); y[7] += bfhi(w3);
                    y[8] += bflo(w4); y[9] += bfhi(w4);
                }
                #pragma unroll
                for (int h = 0; h < 5; ++h) {
                    float o0 = 0.f, o1 = 0.f;
                    #pragma unroll
                    for (int j = 0; j < MN; ++j) {
                        o0 += y[j] * sC2[j * MN + 2*h];
                        o1 += y[j] * sC2[j * MN + 2*h + 1];
                    }
                    unsigned w = PL[h * NN + r];          // own dd row
                    dot += o0 * bflo(w) + o1 * bfhi(w);
                    Db[(size_t)r * 5 + h] = packbf(o0, o1);
                }
            }
            #pragma unroll
            for (int d = 32; d; d >>= 1) dot += __shfl_xor(dot, d);
            if ((tid & 63) == 0) sRed[tid >> 6] = dot;
            __syncthreads();
            if (tid == 0) {
                float s = 0.f;
                for (int w = 0; w < NW; ++w) s += sRed[w];
                sDots[3] = s;
            }
            __syncthreads();
        }
    }

    // ---- F: final tau + objective (T,C from globals; dd from planes; D from Dg) ----
    if (tid == 0) {
        float a = -2.f * alpha * sDots[3];
        float b = oma * sDots[0] + alpha * (sDots[1] - 4.f * sDots[2]);
        float tau;
        if (a > 0.f) tau = fminf(fmaxf(-b / (2.f * a + 1e-16f), 0.f), 1.f);
        else         tau = (a + b < 0.f) ? 1.f : 0.f;
        sBC[0] = tau;
    }
    __syncthreads();
    {
        const float tau = sBC[0];
        float gw = 0.f, wass = 0.f;
        #pragma unroll
        for (int k = 0; k < RPT; ++k) {
            const int r = tid + k * TPB;
            const float cp = (float)degi[r] * invn;
            const size_t bc = (size_t)r * MN;
            #pragma unroll
            for (int h = 0; h < 5; ++h) {
                float2 tv = *(const float2*)(Tb + bc + 2*h);
                float2 cv = *(const float2*)(Cb + bc + 2*h);
                float2 mv = *(const float2*)(Mb + bc + 2*h);
                unsigned dw = PL[h * NN + r];
                unsigned Dw_ = Db[(size_t)r * 5 + h];
                float Tf0 = tv.x + tau * bflo(dw), Tf1 = tv.y + tau * bfhi(dw);
                float Cf0 = cv.x + tau * bflo(Dw_), Cf1 = cv.y + tau * bfhi(Dw_);
                gw   += (cp + scq[2*h]   - 2.f * Cf0) * Tf0
                      + (cp + scq[2*h+1] - 2.f * Cf1) * Tf1;
                wass += mv.x * Tf0 + mv.y * Tf1;
            }
        }
        #pragma unroll
        for (int d = 32; d; d >>= 1) {
            gw   += __shfl_xor(gw, d);
            wass += __shfl_xor(wass, d);
        }
        if ((tid & 63) == 0) { sRed[tid >> 6] = gw; sRed[NW + (tid >> 6)] = wass; }
        __syncthreads();
        if (tid == 0) {
            float g = 0.f, ws = 0.f;
            for (int w = 0; w < NW; ++w) { g += sRed[w]; ws += sRed[NW + w]; }
            out[t] = oma * ws + alpha * g;
        }
    }
}

extern "C" void kernel_launch(void* const* d_in, const int* in_sizes, int n_in,
                              void* d_out, int out_size, void* d_ws, size_t ws_size,
                              hipStream_t stream) {
    const float* x   = (const float*)d_in[0];
    const void*  ei  = d_in[1];
    const float* tpl = (const float*)d_in[2];
    const float* tfp = (const float*)d_in[3];
    const float* q0  = (const float*)d_in[4];
    const float* a0  = (const float*)d_in[5];
    float* outp = (float*)d_out;
    float* Wp   = (float*)d_ws;
    (void)hipFuncSetAttribute(reinterpret_cast<const void*>(&tfgw_kernel),
                              hipFuncAttributeMaxDynamicSharedMemorySize, LDS_DYN);
    void* args[] = { &x, &ei, &tpl, &tfp, &q0, &a0, &outp, &Wp };
    hipLaunchCooperativeKernel(reinterpret_cast<const void*>(&tfgw_kernel),
                               dim3(NBLK), dim3(TPB), args, LDS_DYN, stream);
}

// Round 7
// 936.670 us; speedup vs baseline: 2.8262x; 1.5090x over previous
//
#include <hip/hip_runtime.h>
#include <hip/hip_cooperative_groups.h>

namespace cgx = cooperative_groups;

static constexpr int NN  = 6144;
static constexpr int NE  = 98304;
static constexpr int NF  = 128;
static constexpr int NT  = 16;
static constexpr int MN  = 10;
static constexpr int NCG = 5;
static constexpr int NSK = 50;
static constexpr int WPR = NN / 32;
static constexpr int TPB = 768;
static constexpr int NBLK = 256;
static constexpr int RPT = NN / TPB;   // 8 rows/thread
static constexpr int NW  = TPB / 64;   // 12 waves

static_assert(TPB * RPT == NN, "row mapping");

// workspace layout (float elements); BM (setup-only, 1.18M dwords) aliases
// the Tbf+Cbf+Db region (1.47M dwords) — both dead during setup.
static constexpr size_t OFF_M   = 0;                              // fp32 [NT][NN][10]
static constexpr size_t OFF_T   = OFF_M  + (size_t)NT * NN * MN;  // u32 bf16-pairs [NT][NN][5]
static constexpr size_t OFF_C   = OFF_T  + (size_t)NT * NN * 5;
static constexpr size_t OFF_D   = OFF_C  + (size_t)NT * NN * 5;
static constexpr size_t OFF_RS  = OFF_D  + (size_t)NT * NN * 5;
static constexpr size_t OFF_DEG = OFF_RS + NN;
static constexpr size_t OFF_CI  = OFF_DEG + NN;                   // ushort[2*NE] in NE floats
static constexpr size_t OFF_NNZ = OFF_CI + NE;
// total ~2.7M floats ~= 10.7 MB

static constexpr int LDS_E   = NN * 5 * 4;     // 122880 B: dd/E planes (interleaved pairs)
static constexpr int LDS_SP  = TPB * 11 * 4;   // 33792 B: reduction scatter (stride 11)
static constexpr int LDS_DYN = LDS_E + LDS_SP; // 156672 B

__device__ __forceinline__ unsigned f2bf(float f) {            // fp32 -> bf16 (rne)
    unsigned u = __float_as_uint(f);
    return (u + 0x7fffu + ((u >> 16) & 1u)) >> 16;
}
__device__ __forceinline__ unsigned packbf(float a, float b) { return f2bf(a) | (f2bf(b) << 16); }
__device__ __forceinline__ float bflo(unsigned w) { return __uint_as_float(w << 16); }
__device__ __forceinline__ float bfhi(unsigned w) { return __uint_as_float(w & 0xffff0000u); }
__device__ __forceinline__ void unp4(uint2 w, float* o) {
    o[0] = bflo(w.x); o[1] = bfhi(w.x); o[2] = bflo(w.y); o[3] = bfhi(w.y);
}

extern __shared__ char sMem[];

__global__ __launch_bounds__(TPB) void tfgw_kernel(
    const float* __restrict__ x, const void* __restrict__ eiv,
    const float* __restrict__ tpl, const float* __restrict__ tf,
    const float* __restrict__ q0, const float* __restrict__ a0,
    float* __restrict__ out, float* __restrict__ W)
{
    __shared__ float sC2[MN * MN];
    __shared__ float sq[MN], scq[MN], sqC2[MN], sv[MN], sCv[MN], sNSQ[MN];
    __shared__ float sRed[3 * NW];
    __shared__ float sBC[2];
    __shared__ float sDots[4];

    const int tid = threadIdx.x;
    const int bid = blockIdx.x;

    unsigned* BM    = (unsigned*)(W + OFF_T);   // aliased; dead after setup
    int* rowst      = (int*)(W + OFF_RS);
    int* degi       = (int*)(W + OFF_DEG);
    unsigned short* colix = (unsigned short*)(W + OFF_CI);
    int* nnzc       = (int*)(W + OFF_NNZ);
    float* Mw  = W + OFF_M;
    unsigned* Tg = (unsigned*)(W + OFF_T);
    unsigned* Cg = (unsigned*)(W + OFF_C);
    unsigned* Dg = (unsigned*)(W + OFF_D);

    unsigned* PL01 = (unsigned*)sMem;           // planes 0&1 interleaved: [r] -> dwords 2r,2r+1
    unsigned* PL23 = PL01 + 2 * NN;             // planes 2&3 interleaved
    unsigned* PL4  = PL01 + 4 * NN;             // plane 4
    float* sP      = (float*)(sMem + LDS_E);    // [TPB*11]

    const float alpha  = 1.f / (1.f + __expf(-a0[0]));
    const float invn   = 1.f / (float)NN;
    const float alpha2 = 2.f * alpha;
    const float oma    = 1.f - alpha;

    cgx::grid_group grid = cgx::this_grid();

    // ---- P0: zero bitmap + nnz ----
    for (int idx = bid * TPB + tid; idx < NN * WPR; idx += NBLK * TPB) BM[idx] = 0u;
    if (bid == 0 && tid == 0) *nnzc = 0;
    grid.sync();

    // ---- P1: adjacency bits + feature cost M (sTF overlays sMem) ----
    {
        const unsigned* uw = (const unsigned*)eiv;
        const bool is64 = (uw[1] == 0u && uw[3] == 0u && uw[5] == 0u);
        for (int e = bid * TPB + tid; e < NE; e += NBLK * TPB) {
            int s, d;
            if (is64) {
                s = (int)((const long long*)eiv)[e];
                d = (int)((const long long*)eiv)[NE + e];
            } else {
                s = ((const int*)eiv)[e];
                d = ((const int*)eiv)[NE + e];
            }
            atomicOr(&BM[(size_t)s * WPR + (d >> 5)], 1u << (d & 31));
            atomicOr(&BM[(size_t)d * WPR + (s >> 5)], 1u << (s & 31));
        }
        float* sTF = (float*)sMem;
        const int t = bid >> 4, rb = bid & 15;
        for (int k = tid; k < MN * NF; k += TPB) sTF[k] = tf[t * MN * NF + k];
        __syncthreads();
        if (tid < MN) {
            float s = 0.f;
            for (int k = 0; k < NF; ++k) { float v = sTF[tid * NF + k]; s += v * v; }
            sNSQ[tid] = s;
        }
        __syncthreads();
        if (tid < 384) {
            const int i = rb * 384 + tid;
            const float4* x4 = (const float4*)(x + (size_t)i * NF);
            const float4* t4 = (const float4*)sTF;
            float acc[MN]; float xn = 0.f;
            #pragma unroll
            for (int j = 0; j < MN; ++j) acc[j] = 0.f;
            for (int k4 = 0; k4 < NF / 4; ++k4) {
                float4 xv = x4[k4];
                xn += xv.x * xv.x + xv.y * xv.y + xv.z * xv.z + xv.w * xv.w;
                #pragma unroll
                for (int j = 0; j < MN; ++j) {
                    float4 tv = t4[j * (NF / 4) + k4];
                    acc[j] += xv.x * tv.x + xv.y * tv.y + xv.z * tv.z + xv.w * tv.w;
                }
            }
            float* Mrow = Mw + (size_t)t * NN * MN + (size_t)i * MN;
            #pragma unroll
            for (int j = 0; j < MN; ++j) Mrow[j] = xn + sNSQ[j] - 2.f * acc[j];
        }
    }
    grid.sync();

    // ---- P2: degrees + CSR (ushort cols) ----
    {
        const int i = bid * TPB + tid;
        if (i < NN) {
            int cnt = 0;
            for (int w = 0; w < WPR; ++w) cnt += __popc(BM[(size_t)i * WPR + w]);
            int st = atomicAdd(nnzc, cnt);
            rowst[i] = st; degi[i] = cnt;
            int p = st;
            for (int w = 0; w < WPR; ++w) {
                unsigned m = BM[(size_t)i * WPR + w];
                while (m) { int b = __ffs(m) - 1; m &= m - 1; colix[p++] = (unsigned short)((w << 5) + b); }
            }
        }
    }
    grid.sync();     // last grid sync

    if (bid >= NT) return;

    // ================= block t owns template t =================
    const int t = bid;
    float* Mb = Mw + (size_t)t * NN * MN;
    unsigned* Tb = Tg + (size_t)t * NN * 5;
    unsigned* Cb = Cg + (size_t)t * NN * 5;
    unsigned* Db = Dg + (size_t)t * NN * 5;

    if (tid == 0) {
        float qv[MN]; float qm = -1e30f;
        for (int j = 0; j < MN; ++j) { qv[j] = q0[t * MN + j]; qm = fmaxf(qm, qv[j]); }
        float qs = 0.f;
        for (int j = 0; j < MN; ++j) { qv[j] = __expf(qv[j] - qm); qs += qv[j]; }
        for (int j = 0; j < MN; ++j) { qv[j] /= qs; sq[j] = qv[j]; }
        for (int j = 0; j < MN; ++j) {
            float s2 = 0.f, s1 = 0.f;
            for (int k = 0; k < MN; ++k) {
                float cjk = tpl[t * MN * MN + j * MN + k];
                s2 += cjk * cjk * qv[k];
                s1 += tpl[t * MN * MN + k * MN + j] * qv[k];
            }
            scq[j] = s2; sqC2[j] = s1;
        }
    }
    for (int k = tid; k < MN * MN; k += TPB) sC2[k] = tpl[t * MN * MN + k];
    __syncthreads();

    float uu[RPT];

    for (int cgi = 0; cgi < NCG; ++cgi) {
        // ---- tau from previous dots; tau==0 (cgi>0) => fixed point, done ----
        if (tid == 0) {
            float tau = 0.f;
            if (cgi > 0) {
                float a = -2.f * alpha * sDots[3];
                float b = oma * sDots[0] + alpha * (sDots[1] - 4.f * sDots[2]);
                if (a > 0.f) tau = fminf(fmaxf(-b / (2.f * a + 1e-16f), 0.f), 1.f);
                else         tau = (a + b < 0.f) ? 1.f : 0.f;
            }
            sBC[0] = tau;
        }
        __syncthreads();
        const float tau = sBC[0];
        if (cgi > 0 && tau == 0.f) break;   // provable no-op from here on

        // ---- Phase A: update T,C (bf16 globals; dd from own LDS rows); g -> planes ----
        float gmax = 0.f;
        #pragma unroll
        for (int k = 0; k < RPT; ++k) {
            const int r = tid + k * TPB;
            const float cp = (float)degi[r] * invn;
            const size_t b5 = (size_t)r * 5;
            float T[MN], C[MN];
            if (cgi == 0) {
                #pragma unroll
                for (int j = 0; j < MN; ++j) { T[j] = sq[j] * invn; C[j] = cp * sqC2[j]; }
                #pragma unroll
                for (int h = 0; h < 5; ++h) {
                    unsigned tw = packbf(T[2*h], T[2*h+1]);
                    unsigned cw = packbf(C[2*h], C[2*h+1]);
                    Tb[b5 + h] = tw; Cb[b5 + h] = cw;
                    T[2*h] = bflo(tw); T[2*h+1] = bfhi(tw);
                    C[2*h] = bflo(cw); C[2*h+1] = bfhi(cw);
                }
            } else {
                float dd[MN];
                uint2 a01 = *(const uint2*)(PL01 + 2 * r);
                uint2 a23 = *(const uint2*)(PL23 + 2 * r);
                unsigned a4 = PL4[r];
                unp4(a01, dd); unp4(a23, dd + 4); dd[8] = bflo(a4); dd[9] = bfhi(a4);
                #pragma unroll
                for (int h = 0; h < 5; ++h) {
                    unsigned tw = Tb[b5 + h], cw = Cb[b5 + h], Dw = Db[b5 + h];
                    float T0 = bflo(tw) + tau * dd[2*h];
                    float T1 = bfhi(tw) + tau * dd[2*h+1];
                    float C0 = bflo(cw) + tau * bflo(Dw);
                    float C1v = bfhi(cw) + tau * bfhi(Dw);
                    unsigned ntw = packbf(T0, T1), ncw = packbf(C0, C1v);
                    Tb[b5 + h] = ntw; Cb[b5 + h] = ncw;
                    C[2*h] = bflo(ncw); C[2*h+1] = bfhi(ncw);
                }
            }
            float g[MN];
            #pragma unroll
            for (int h = 0; h < 5; ++h) {
                float2 mv = *(const float2*)(Mb + (size_t)r * MN + 2*h);
                g[2*h]   = oma * mv.x + alpha2 * (cp + scq[2*h]   - 2.f * C[2*h]);
                g[2*h+1] = oma * mv.y + alpha2 * (cp + scq[2*h+1] - 2.f * C[2*h+1]);
                gmax = fmaxf(gmax, fmaxf(__builtin_fabsf(g[2*h]), __builtin_fabsf(g[2*h+1])));
            }
            *(uint2*)(PL01 + 2 * r) = make_uint2(packbf(g[0], g[1]), packbf(g[2], g[3]));
            *(uint2*)(PL23 + 2 * r) = make_uint2(packbf(g[4], g[5]), packbf(g[6], g[7]));
            PL4[r] = packbf(g[8], g[9]);
        }
        #pragma unroll
        for (int d = 32; d; d >>= 1) gmax = fmaxf(gmax, __shfl_xor(gmax, d));
        if ((tid & 63) == 0) sRed[tid >> 6] = gmax;
        __syncthreads();
        if (tid == 0) {
            float m = sRed[0];
            for (int w = 1; w < NW; ++w) m = fmaxf(m, sRed[w]);
            sBC[1] = 1.f / (0.05f * m + 1e-8f);
        }
        __syncthreads();
        const float invreg = sBC[1];

        // ---- Phase B: E = exp(-g*invreg), in place (own rows; LDS-only) ----
        #pragma unroll
        for (int k = 0; k < RPT; ++k) {
            const int r = tid + k * TPB;
            float g[MN];
            uint2 a01 = *(const uint2*)(PL01 + 2 * r);
            uint2 a23 = *(const uint2*)(PL23 + 2 * r);
            unsigned a4 = PL4[r];
            unp4(a01, g); unp4(a23, g + 4); g[8] = bflo(a4); g[9] = bfhi(a4);
            float e[MN];
            #pragma unroll
            for (int j = 0; j < MN; ++j) e[j] = __expf(-g[j] * invreg);
            *(uint2*)(PL01 + 2 * r) = make_uint2(packbf(e[0], e[1]), packbf(e[2], e[3]));
            *(uint2*)(PL23 + 2 * r) = make_uint2(packbf(e[4], e[5]), packbf(e[6], e[7]));
            PL4[r] = packbf(e[8], e[9]);
        }

        // ---- Sinkhorn iter 0 (u = 1) ----
        {
            float a[MN];
            #pragma unroll
            for (int j = 0; j < MN; ++j) a[j] = 0.f;
            #pragma unroll
            for (int k = 0; k < RPT; ++k) {
                const int r = tid + k * TPB;
                float e[MN];
                uint2 a01 = *(const uint2*)(PL01 + 2 * r);
                uint2 a23 = *(const uint2*)(PL23 + 2 * r);
                unsigned a4 = PL4[r];
                unp4(a01, e); unp4(a23, e + 4); e[8] = bflo(a4); e[9] = bfhi(a4);
                #pragma unroll
                for (int j = 0; j < MN; ++j) a[j] += e[j];
            }
            #pragma unroll
            for (int j = 0; j < MN; ++j) sP[tid * 11 + j] = a[j];
            __syncthreads();
            if (tid < 640) {
                const int j = tid >> 6, c = tid & 63;
                float s = 0.f;
                #pragma unroll
                for (int kk = 0; kk < NW; ++kk) s += sP[(c + (kk << 6)) * 11 + j];
                #pragma unroll
                for (int d = 32; d; d >>= 1) s += __shfl_xor(s, d);
                if (c == 0) { sv[j] = sq[j] / s; sCv[j] = 0.f; }
            }
            __syncthreads();
        }

        // ---- Sinkhorn fused (u,v) x50, early exit on v fixed point ----
        for (int it = 1; it <= NSK; ++it) {
            float vv[MN];
            #pragma unroll
            for (int j = 0; j < MN; ++j) vv[j] = sv[j];
            float a[MN];
            #pragma unroll
            for (int j = 0; j < MN; ++j) a[j] = 0.f;
            #pragma unroll
            for (int k = 0; k < RPT; ++k) {
                const int r = tid + k * TPB;
                float e[MN];
                uint2 a01 = *(const uint2*)(PL01 + 2 * r);
                uint2 a23 = *(const uint2*)(PL23 + 2 * r);
                unsigned a4 = PL4[r];
                unp4(a01, e); unp4(a23, e + 4); e[8] = bflo(a4); e[9] = bfhi(a4);
                float R = 0.f;
                #pragma unroll
                for (int j = 0; j < MN; ++j) R += e[j] * vv[j];
                const float u = invn * __builtin_amdgcn_rcpf(R);
                uu[k] = u;
                #pragma unroll
                for (int j = 0; j < MN; ++j) a[j] += e[j] * u;
            }
            #pragma unroll
            for (int j = 0; j < MN; ++j) sP[tid * 11 + j] = a[j];
            __syncthreads();
            if (tid < 640) {
                const int j = tid >> 6, c = tid & 63;
                float s = 0.f;
                #pragma unroll
                for (int kk = 0; kk < NW; ++kk) s += sP[(c + (kk << 6)) * 11 + j];
                #pragma unroll
                for (int d = 32; d; d >>= 1) s += __shfl_xor(s, d);
                if (c == 0) {
                    float vold = sv[j];
                    float vnew = sq[j] / s;
                    sCv[j] = (__builtin_fabsf(vnew - vold) <= 3e-6f * vnew) ? 1.f : 0.f;
                    sv[j] = vnew;
                }
            }
            __syncthreads();
            float cs = 0.f;
            #pragma unroll
            for (int j = 0; j < MN; ++j) cs += sCv[j];
            if (cs == 10.f) break;
        }

        // ---- dT phase: dd = u*E*v - T; dots; planes <- dd(bf16) ----
        {
            float vv[MN];
            #pragma unroll
            for (int j = 0; j < MN; ++j) vv[j] = sv[j];
            float sMdT = 0.f, sCdT = 0.f, sCTdT = 0.f;
            #pragma unroll
            for (int k = 0; k < RPT; ++k) {
                const int r = tid + k * TPB;
                const float cp = (float)degi[r] * invn;
                const size_t b5 = (size_t)r * 5;
                const float u = uu[k];
                float e[MN], dd[MN];
                uint2 a01 = *(const uint2*)(PL01 + 2 * r);
                uint2 a23 = *(const uint2*)(PL23 + 2 * r);
                unsigned a4 = PL4[r];
                unp4(a01, e); unp4(a23, e + 4); e[8] = bflo(a4); e[9] = bfhi(a4);
                #pragma unroll
                for (int h = 0; h < 5; ++h) {
                    unsigned tw = Tb[b5 + h], cw = Cb[b5 + h];
                    float2 mv = *(const float2*)(Mb + (size_t)r * MN + 2*h);
                    float d0 = u * e[2*h]   * vv[2*h]   - bflo(tw);
                    float d1 = u * e[2*h+1] * vv[2*h+1] - bfhi(tw);
                    dd[2*h] = d0; dd[2*h+1] = d1;
                    sMdT  += mv.x * d0 + mv.y * d1;
                    sCdT  += (cp + scq[2*h]) * d0 + (cp + scq[2*h+1]) * d1;
                    sCTdT += bflo(cw) * d0 + bfhi(cw) * d1;
                }
                *(uint2*)(PL01 + 2 * r) = make_uint2(packbf(dd[0], dd[1]), packbf(dd[2], dd[3]));
                *(uint2*)(PL23 + 2 * r) = make_uint2(packbf(dd[4], dd[5]), packbf(dd[6], dd[7]));
                PL4[r] = packbf(dd[8], dd[9]);
            }
            #pragma unroll
            for (int d = 32; d; d >>= 1) {
                sMdT  += __shfl_xor(sMdT, d);
                sCdT  += __shfl_xor(sCdT, d);
                sCTdT += __shfl_xor(sCTdT, d);
            }
            if ((tid & 63) == 0) {
                const int w = tid >> 6;
                sRed[w] = sMdT; sRed[NW + w] = sCdT; sRed[2*NW + w] = sCTdT;
            }
            __syncthreads();   // dots staged AND dd planes visible block-wide
            if (tid == 0) {
                float r0 = 0.f, r1 = 0.f, r2 = 0.f;
                for (int w = 0; w < NW; ++w) { r0 += sRed[w]; r1 += sRed[NW+w]; r2 += sRed[2*NW+w]; }
                sDots[0] = r0; sDots[1] = r1; sDots[2] = r2;
            }
        }

        // ---- SpMM: D = C1 dT C2 (gather dd planes), sA = <D,dd>; Db <- bf16 ----
        {
            float dot = 0.f;
            #pragma unroll
            for (int k = 0; k < RPT; ++k) {
                const int r = tid + k * TPB;
                float y[MN];
                #pragma unroll
                for (int j = 0; j < MN; ++j) y[j] = 0.f;
                const int st = rowst[r], dg = degi[r];
                const unsigned short* cl = colix + st;
                for (int e = 0; e < dg; ++e) {
                    const int j = cl[e];
                    uint2 a01 = *(const uint2*)(PL01 + 2 * j);
                    uint2 a23 = *(const uint2*)(PL23 + 2 * j);
                    unsigned a4 = PL4[j];
                    y[0] += bflo(a01.x); y[1] += bfhi(a01.x);
                    y[2] += bflo(a01.y); y[3] += bfhi(a01.y);
                    y[4] += bflo(a23.x); y[5] += bfhi(a23.x);
                    y[6] += bflo(a23.y); y[7] += bfhi(a23.y);
                    y[8] += bflo(a4);    y[9] += bfhi(a4);
                }
                float dd[MN];
                uint2 a01 = *(const uint2*)(PL01 + 2 * r);
                uint2 a23 = *(const uint2*)(PL23 + 2 * r);
                unsigned a4 = PL4[r];
                unp4(a01, dd); unp4(a23, dd + 4); dd[8] = bflo(a4); dd[9] = bfhi(a4);
                #pragma unroll
                for (int h = 0; h < 5; ++h) {
                    float o0 = 0.f, o1 = 0.f;
                    #pragma unroll
                    for (int j = 0; j < MN; ++j) {
                        o0 += y[j] * sC2[j * MN + 2*h];
                        o1 += y[j] * sC2[j * MN + 2*h + 1];
                    }
                    dot += o0 * dd[2*h] + o1 * dd[2*h+1];
                    Db[(size_t)r * 5 + h] = packbf(o0, o1);
                }
            }
            #pragma unroll
            for (int d = 32; d; d >>= 1) dot += __shfl_xor(dot, d);
            if ((tid & 63) == 0) sRed[tid >> 6] = dot;
            __syncthreads();
            if (tid == 0) {
                float s = 0.f;
                for (int w = 0; w < NW; ++w) s += sRed[w];
                sDots[3] = s;
            }
            __syncthreads();
        }
    }

    // ---- F: final tau + objective (T,C,D from bf16 globals; dd from planes) ----
    if (tid == 0) {
        float a = -2.f * alpha * sDots[3];
        float b = oma * sDots[0] + alpha * (sDots[1] - 4.f * sDots[2]);
        float tau;
        if (a > 0.f) tau = fminf(fmaxf(-b / (2.f * a + 1e-16f), 0.f), 1.f);
        else         tau = (a + b < 0.f) ? 1.f : 0.f;
        sBC[0] = tau;
    }
    __syncthreads();
    {
        const float tau = sBC[0];
        float gw = 0.f, wass = 0.f;
        #pragma unroll
        for (int k = 0; k < RPT; ++k) {
            const int r = tid + k * TPB;
            const float cp = (float)degi[r] * invn;
            const size_t b5 = (size_t)r * 5;
            float dd[MN];
            uint2 a01 = *(const uint2*)(PL01 + 2 * r);
            uint2 a23 = *(const uint2*)(PL23 + 2 * r);
            unsigned a4 = PL4[r];
            unp4(a01, dd); unp4(a23, dd + 4); dd[8] = bflo(a4); dd[9] = bfhi(a4);
            #pragma unroll
            for (int h = 0; h < 5; ++h) {
                unsigned tw = Tb[b5 + h], cw = Cb[b5 + h], Dw = Db[b5 + h];
                float2 mv = *(const float2*)(Mb + (size_t)r * MN + 2*h);
                float Tf0 = bflo(tw) + tau * dd[2*h];
                float Tf1 = bfhi(tw) + tau * dd[2*h+1];
                float Cf0 = bflo(cw) + tau * bflo(Dw);
                float Cf1 = bfhi(cw) + tau * bfhi(Dw);
                gw   += (cp + scq[2*h]   - 2.f * Cf0) * Tf0
                      + (cp + scq[2*h+1] - 2.f * Cf1) * Tf1;
                wass += mv.x * Tf0 + mv.y * Tf1;
            }
        }
        #pragma unroll
        for (int d = 32; d; d >>= 1) {
            gw   += __shfl_xor(gw, d);
            wass += __shfl_xor(wass, d);
        }
        if ((tid & 63) == 0) { sRed[tid >> 6] = gw; sRed[NW + (tid >> 6)] = wass; }
        __syncthreads();
        if (tid == 0) {
            float g = 0.f, ws = 0.f;
            for (int w = 0; w < NW; ++w) { g += sRed[w]; ws += sRed[NW + w]; }
            out[t] = oma * ws + alpha * g;
        }
    }
}

extern "C" void kernel_launch(void* const* d_in, const int* in_sizes, int n_in,
                              void* d_out, int out_size, void* d_ws, size_t ws_size,
                              hipStream_t stream) {
    const float* x   = (const float*)d_in[0];
    const void*  ei  = d_in[1];
    const float* tpl = (const float*)d_in[2];
    const float* tfp = (const float*)d_in[3];
    const float* q0  = (const float*)d_in[4];
    const float* a0  = (const float*)d_in[5];
    float* outp = (float*)d_out;
    float* Wp   = (float*)d_ws;
    (void)hipFuncSetAttribute(reinterpret_cast<const void*>(&tfgw_kernel),
                              hipFuncAttributeMaxDynamicSharedMemorySize, LDS_DYN);
    void* args[] = { &x, &ei, &tpl, &tfp, &q0, &a0, &outp, &Wp };
    hipLaunchCooperativeKernel(reinterpret_cast<const void*>(&tfgw_kernel),
                               dim3(NBLK), dim3(TPB), args, LDS_DYN, stream);
}